// Round 4
// baseline (293.712 us; speedup 1.0000x reference)
//
#include <hip/hip_runtime.h>

#define NB 8
#define CC 256
#define NN 4096
#define KVB 64
#define NT (NN / KVB)

typedef __attribute__((ext_vector_type(8))) __bf16 bf16x8;
typedef __attribute__((ext_vector_type(4))) float f32x4;
typedef unsigned short u16;
typedef unsigned int u32;

#define GLL(g, l) __builtin_amdgcn_global_load_lds(                         \
    (const __attribute__((address_space(1))) void*)(g),                     \
    (__attribute__((address_space(3))) void*)(l), 16, 0, 0)

static __device__ __forceinline__ u16 f2b(float f) {
  unsigned u = __float_as_uint(f);
  u += 0x7FFF + ((u >> 16) & 1);   // round-to-nearest-even
  return (u16)(u >> 16);
}

// ---------------- kernel 1: transpose + convert x (b,c,n) f32 -> xb (b,n,c) bf16
__global__ __launch_bounds__(256) void k_prep(const float* __restrict__ x,
                                              u16* __restrict__ xb) {
  __shared__ float tile[64][65];
  const int b = blockIdx.z, c0 = blockIdx.y * 64, n0 = blockIdx.x * 64;
  const int t = threadIdx.x, j = t & 63, i0 = t >> 6;
  const float* xp = x + ((size_t)b * CC + c0) * NN + n0;
#pragma unroll
  for (int i = i0; i < 64; i += 4) tile[i][j] = xp[(size_t)i * NN + j];
  __syncthreads();
  u16* op = xb + ((size_t)b * NN + n0) * CC + c0;
#pragma unroll
  for (int r = i0; r < 64; r += 4) op[(size_t)r * CC + j] = f2b(tile[j][r]);
}

// ---------------- kernel 2: convert weights to bf16
__global__ __launch_bounds__(256) void k_cvtw(const float* __restrict__ wq,
                                              const float* __restrict__ wk,
                                              const float* __restrict__ wv,
                                              u16* __restrict__ wb) {
  const int i = blockIdx.x * 256 + threadIdx.x;
  const int z = blockIdx.y;
  const float* s = z == 0 ? wq : (z == 1 ? wk : wv);
  wb[(size_t)z * CC * CC + i] = f2b(s[i]);
}

// ---------------- kernel 3: QKV projection GEMM
// z=0 -> Q (b,n,c) scaled by log2e/16; z=1 -> K (b,n,c); z=2 -> V^T (b,c,n)
__global__ __launch_bounds__(256) void k_proj(const u16* __restrict__ xb,
                                              const u16* __restrict__ wb,
                                              const float* __restrict__ bq,
                                              const float* __restrict__ bk,
                                              const float* __restrict__ bv,
                                              u16* __restrict__ Qb,
                                              u16* __restrict__ Kb,
                                              u16* __restrict__ VTb) {
  const int z = blockIdx.z, b = blockIdx.y, n0 = blockIdx.x * 64;
  const u16* w = wb + (size_t)z * CC * CC;
  const float* bias = z == 0 ? bq : (z == 1 ? bk : bv);
  const float sc = z == 0 ? 0.09016844136959962f : 1.0f;  // log2(e)/16
  const int wid = threadIdx.x >> 6, lane = threadIdx.x & 63;
  const int lr = lane & 15, lq = lane >> 4;
  const int i0 = wid * 64;
  const u16* A = xb + ((size_t)b * NN + n0) * CC;

  f32x4 acc[4][4];
#pragma unroll
  for (int mt = 0; mt < 4; ++mt)
#pragma unroll
    for (int it = 0; it < 4; ++it) acc[mt][it] = (f32x4){0.f, 0.f, 0.f, 0.f};

#pragma unroll
  for (int s = 0; s < 8; ++s) {
    const int kb = s * 32 + lq * 8;
    bf16x8 av[4], bm[4];
#pragma unroll
    for (int mt = 0; mt < 4; ++mt)
      av[mt] = *(const bf16x8*)(A + (size_t)(mt * 16 + lr) * CC + kb);
#pragma unroll
    for (int it = 0; it < 4; ++it)
      bm[it] = *(const bf16x8*)(w + (size_t)(i0 + it * 16 + lr) * CC + kb);
#pragma unroll
    for (int mt = 0; mt < 4; ++mt)
#pragma unroll
      for (int it = 0; it < 4; ++it)
        acc[mt][it] = __builtin_amdgcn_mfma_f32_16x16x32_bf16(av[mt], bm[it], acc[mt][it], 0, 0, 0);
  }

#pragma unroll
  for (int it = 0; it < 4; ++it) {
    const int i = i0 + it * 16 + lr;
    const float bb = bias[i];
#pragma unroll
    for (int mt = 0; mt < 4; ++mt) {
      f32x4 v = acc[mt][it];
      if (z == 2) {
        ushort4 p;
        p.x = f2b(v[0] + bb);
        p.y = f2b(v[1] + bb);
        p.z = f2b(v[2] + bb);
        p.w = f2b(v[3] + bb);
        *(ushort4*)(VTb + ((size_t)b * CC + i) * NN + n0 + mt * 16 + lq * 4) = p;
      } else {
        u16* O = (z == 0 ? Qb : Kb) + ((size_t)b * NN + n0 + mt * 16 + lq * 4) * CC + i;
#pragma unroll
        for (int r = 0; r < 4; ++r) O[(size_t)r * CC] = f2b((v[r] + bb) * sc);
      }
    }
  }
}

// ---------------- kernel 4: flash attention
// 8 waves = 4 q-groups x 2 kv-groups. Wave: 32 q-rows, 32 kv per tile.
// KVB=64 staged dbuf + counted vmcnt; swapped QK^T; in-reg softmax per
// kv-group; LDS merge epilogue across kv-groups.
__global__ __launch_bounds__(512, 2) void k_attn(const u16* __restrict__ Qb,
                                                 const u16* __restrict__ Kb,
                                                 const u16* __restrict__ VTb,
                                                 float* __restrict__ out) {
  // [0,64K): Kt bufs (2 x 32KB, rows 512B, XOR-swz); [64K,128K): Vt bufs.
  // After the loop the same 128KB is reused as Os (per-qg 32KB fp32 partials).
  __shared__ __align__(16) char smem[131072];
  __shared__ float m_s[2][128];
  __shared__ float l_s[2][128];

  const int bid = blockIdx.x;
  const int b = bid & 7;                 // batch -> XCD pin
  const int q0 = (bid >> 3) * 128;
  const int tid = threadIdx.x;
  const int wid = tid >> 6, lane = tid & 63;
  const int lr = lane & 15, lq = lane >> 4;
  const int kvg = wid & 1, qg = wid >> 1;

  const char* Kbase = (const char*)(Kb + (size_t)b * NN * CC);
  const char* Vbase = (const char*)(VTb + (size_t)b * CC * NN);

  const int kc0 = wid * 4;           // 4 K-chunks + 4 V-chunks (1KB) per wave
  const int krow_off = lane >> 5;
  const int kbyt = (lane & 31) * 16;
  const int vrow_off = lane >> 3;
  const int vbyt = (lane & 7) * 16;

  auto stage = [&](int buf, int kv) {
#pragma unroll
    for (int i = 0; i < 4; ++i) {
      const int c = kc0 + i;
      const int row = c * 2 + krow_off;
      GLL(Kbase + (size_t)(kv + row) * (CC * 2) + (kbyt ^ ((row & 7) << 4)),
          smem + buf * 32768 + c * 1024);
      const int vr = c * 8 + vrow_off;
      GLL(Vbase + (size_t)vr * (NN * 2) + (size_t)kv * 2 + (vbyt ^ ((vr & 7) << 4)),
          smem + 65536 + buf * 32768 + c * 1024);
    }
  };

  stage(0, 0);  // prologue

  // hoist Q (32 rows x 256, pre-scaled by log2e/16): qf[qt*8+s]
  bf16x8 qf[16];
  {
    const u16* Qp = Qb + ((size_t)b * NN + q0 + qg * 32 + lr) * CC + lq * 8;
#pragma unroll
    for (int qt = 0; qt < 2; ++qt)
#pragma unroll
      for (int s = 0; s < 8; ++s)
        qf[qt * 8 + s] = *(const bf16x8*)(Qp + (size_t)qt * 16 * CC + s * 32);
  }

  f32x4 oacc[2][16];
#pragma unroll
  for (int qt = 0; qt < 2; ++qt)
#pragma unroll
    for (int ct = 0; ct < 16; ++ct) oacc[qt][ct] = (f32x4){0.f, 0.f, 0.f, 0.f};
  float mrow[2] = {-1e30f, -1e30f};   // running max (log2 units), q-col = qt*16+lr
  float lpart[2] = {0.f, 0.f};

  for (int t = 0; t < NT; ++t) {
    const int cur = t & 1;
    if (t + 1 < NT) {
      stage(cur ^ 1, (t + 1) * KVB);
      asm volatile("s_waitcnt vmcnt(8)" ::: "memory");
    } else {
      asm volatile("s_waitcnt vmcnt(0)" ::: "memory");
    }
    __builtin_amdgcn_s_barrier();

    // ---- S^T = K Q^T over this wave's kv-half (32 kv x 32 q)
    f32x4 sacc[2][2];
#pragma unroll
    for (int kvt = 0; kvt < 2; ++kvt)
#pragma unroll
      for (int qt = 0; qt < 2; ++qt) sacc[kvt][qt] = (f32x4){0.f, 0.f, 0.f, 0.f};
    __builtin_amdgcn_s_setprio(1);
#pragma unroll
    for (int s = 0; s < 8; ++s) {
      const int cb = s * 64 + lq * 16;
#pragma unroll
      for (int kvt = 0; kvt < 2; ++kvt) {
        const int row = kvg * 32 + kvt * 16 + lr;
        const bf16x8 kf = *(const bf16x8*)(smem + cur * 32768 +
                                           row * 512 + (cb ^ ((row & 7) << 4)));
        sacc[kvt][0] = __builtin_amdgcn_mfma_f32_16x16x32_bf16(kf, qf[s], sacc[kvt][0], 0, 0, 0);
        sacc[kvt][1] = __builtin_amdgcn_mfma_f32_16x16x32_bf16(kf, qf[8 + s], sacc[kvt][1], 0, 0, 0);
      }
    }
    __builtin_amdgcn_s_setprio(0);

    // ---- per-qt tile max over this kv-half (in-lane 8 + xor16 + xor32)
    float pmax[2];
#pragma unroll
    for (int qt = 0; qt < 2; ++qt) {
      float mx = fmaxf(fmaxf(fmaxf(sacc[0][qt][0], sacc[0][qt][1]),
                             fmaxf(sacc[0][qt][2], sacc[0][qt][3])),
                       fmaxf(fmaxf(sacc[1][qt][0], sacc[1][qt][1]),
                             fmaxf(sacc[1][qt][2], sacc[1][qt][3])));
      mx = fmaxf(mx, __shfl_xor(mx, 16));
      mx = fmaxf(mx, __shfl_xor(mx, 32));
      pmax[qt] = mx;
    }

    // ---- defer-max rescale (THR = 8*log2e)
    if (!__all(pmax[0] <= mrow[0] + 11.54f && pmax[1] <= mrow[1] + 11.54f)) {
#pragma unroll
      for (int qt = 0; qt < 2; ++qt) {
        const float nm = fmaxf(mrow[qt], pmax[qt]);
        const float al = __builtin_amdgcn_exp2f(mrow[qt] - nm);
        mrow[qt] = nm;
        lpart[qt] *= al;
#pragma unroll
        for (int r = 0; r < 4; ++r) {
          const float alr = __shfl(al, lq * 20 + r);
#pragma unroll
          for (int ct = 0; ct < 16; ++ct) oacc[qt][ct][r] *= alr;
        }
      }
    }

    // ---- P = 2^(S-m): pack + permlane/swizzle dance -> PV A-frags
    union { u32 u[4]; bf16x8 v; } pa[2];
    const bool odd = (lq & 1);
#pragma unroll
    for (int qt = 0; qt < 2; ++qt) {
      u32 w2[4];
#pragma unroll
      for (int kvt = 0; kvt < 2; ++kvt) {
        const float p0 = __builtin_amdgcn_exp2f(sacc[kvt][qt][0] - mrow[qt]);
        const float p1 = __builtin_amdgcn_exp2f(sacc[kvt][qt][1] - mrow[qt]);
        const float p2 = __builtin_amdgcn_exp2f(sacc[kvt][qt][2] - mrow[qt]);
        const float p3 = __builtin_amdgcn_exp2f(sacc[kvt][qt][3] - mrow[qt]);
        lpart[qt] += (p0 + p1) + (p2 + p3);
        __bf16 b0 = (__bf16)p0, b1 = (__bf16)p1, b2 = (__bf16)p2, b3 = (__bf16)p3;
        w2[kvt * 2]     = (u32)__builtin_bit_cast(u16, b0) | ((u32)__builtin_bit_cast(u16, b1) << 16);
        w2[kvt * 2 + 1] = (u32)__builtin_bit_cast(u16, b2) | ((u32)__builtin_bit_cast(u16, b3) << 16);
      }
#pragma unroll
      for (int h = 0; h < 2; ++h) {
        u32 A = w2[h], B = w2[2 + h];
        asm volatile("v_permlane32_swap_b32 %0, %1" : "+v"(A), "+v"(B));
        const u32 A16 = __builtin_amdgcn_ds_swizzle(A, 0x401F);  // xor lane^16
        const u32 B16 = __builtin_amdgcn_ds_swizzle(B, 0x401F);
        pa[qt].u[h] = odd ? B16 : A;
        pa[qt].u[2 + h] = odd ? B : A16;
      }
    }

    // ---- O += P V over this kv-half (V^T from swizzled LDS)
    __builtin_amdgcn_s_setprio(1);
#pragma unroll
    for (int ct = 0; ct < 16; ++ct) {
      const int row = ct * 16 + lr;
      const bf16x8 vf = *(const bf16x8*)(smem + 65536 + cur * 32768 + row * 128 +
                                         ((kvg * 64 + lq * 16) ^ ((row & 7) << 4)));
      oacc[0][ct] = __builtin_amdgcn_mfma_f32_16x16x32_bf16(pa[0].v, vf, oacc[0][ct], 0, 0, 0);
      oacc[1][ct] = __builtin_amdgcn_mfma_f32_16x16x32_bf16(pa[1].v, vf, oacc[1][ct], 0, 0, 0);
    }
    __builtin_amdgcn_s_setprio(0);

    asm volatile("" ::: "memory");
    __builtin_amdgcn_s_barrier();
  }

  // ---- epilogue: finish per-group sums, publish stats
#pragma unroll
  for (int qt = 0; qt < 2; ++qt) {
    lpart[qt] += __shfl_xor(lpart[qt], 16);
    lpart[qt] += __shfl_xor(lpart[qt], 32);
  }
  if (lq == 0) {
#pragma unroll
    for (int qt = 0; qt < 2; ++qt) {
      m_s[kvg][qg * 32 + qt * 16 + lr] = mrow[qt];
      l_s[kvg][qg * 32 + qt * 16 + lr] = lpart[qt];
    }
  }
  __syncthreads();  // stats visible; all waves done with Kt/Vt

  // merge factors: gamma = exp2(m_own - m*) / l*, per oacc row (qt, r)
  float gam[2][4];
#pragma unroll
  for (int qt = 0; qt < 2; ++qt)
#pragma unroll
    for (int r = 0; r < 4; ++r) {
      const int idx = qg * 32 + qt * 16 + lq * 4 + r;
      const float m0 = m_s[0][idx], m1 = m_s[1][idx];
      const float ms = fmaxf(m0, m1);
      const float e0 = __builtin_amdgcn_exp2f(m0 - ms);
      const float e1 = __builtin_amdgcn_exp2f(m1 - ms);
      const float linv = 1.f / (l_s[0][idx] * e0 + l_s[1][idx] * e1);
      gam[qt][r] = (kvg ? e1 : e0) * linv;
    }

  // kv-group 1 writes scaled partials to Os (reusing K/V LDS), group 0 merges
  float* dummy;
  (void)dummy;
#pragma unroll
  for (int qt = 0; qt < 2; ++qt) {}
  if (kvg == 1) {
#pragma unroll
    for (int qt = 0; qt < 2; ++qt)
#pragma unroll
      for (int ct = 0; ct < 16; ++ct) {
        const int c = ct * 16 + lr;
        f32x4 v = {oacc[qt][ct][0] * gam[qt][0], oacc[qt][ct][1] * gam[qt][1],
                   oacc[qt][ct][2] * gam[qt][2], oacc[qt][ct][3] * gam[qt][3]};
        *(f32x4*)(smem + qg * 32768 + c * 128 +
                  ((qt * 64 + lq * 16) ^ ((c & 7) << 4))) = v;
      }
  }
  __syncthreads();
  if (kvg == 0) {
    float* op = out + (size_t)b * CC * NN;
    const int nb = q0 + qg * 32;
#pragma unroll
    for (int qt = 0; qt < 2; ++qt)
#pragma unroll
      for (int ct = 0; ct < 16; ++ct) {
        const int c = ct * 16 + lr;
        const f32x4 o1 = *(const f32x4*)(smem + qg * 32768 + c * 128 +
                                         ((qt * 64 + lq * 16) ^ ((c & 7) << 4)));
        f32x4 v = {oacc[qt][ct][0] * gam[qt][0] + o1[0],
                   oacc[qt][ct][1] * gam[qt][1] + o1[1],
                   oacc[qt][ct][2] * gam[qt][2] + o1[2],
                   oacc[qt][ct][3] * gam[qt][3] + o1[3]};
        *(f32x4*)(op + (size_t)c * NN + nb + qt * 16 + lq * 4) = v;
      }
  }
}

extern "C" void kernel_launch(void* const* d_in, const int* in_sizes, int n_in,
                              void* d_out, int out_size, void* d_ws, size_t ws_size,
                              hipStream_t stream) {
  const float* x = (const float*)d_in[0];
  const float* wq = (const float*)d_in[1];
  const float* wk = (const float*)d_in[2];
  const float* wv = (const float*)d_in[3];
  const float* bq = (const float*)d_in[4];
  const float* bk = (const float*)d_in[5];
  const float* bv = (const float*)d_in[6];
  float* out = (float*)d_out;

  u16* Qb = (u16*)d_ws;
  u16* Kb = Qb + (size_t)NB * NN * CC;
  u16* VTb = Kb + (size_t)NB * NN * CC;
  u16* wb = VTb + (size_t)NB * NN * CC;
  u16* xb = (u16*)d_out;  // dead before k_attn writes out

  k_prep<<<dim3(NN / 64, CC / 64, NB), 256, 0, stream>>>(x, xb);
  k_cvtw<<<dim3(CC * CC / 256, 3), 256, 0, stream>>>(wq, wk, wv, wb);
  k_proj<<<dim3(NN / 64, NB, 3), 256, 0, stream>>>(xb, wb, bq, bk, bv, Qb, Kb, VTb);
  k_attn<<<dim3(NN / 128 * NB), 512, 0, stream>>>(Qb, Kb, VTb, out);
}